// Round 3
// baseline (230.394 us; speedup 1.0000x reference)
//
#include <hip/hip_runtime.h>

// CRF forward logZ. Inputs: words i32 [2048][256], ThetaB f32 [64][128],
// WA f32 [64][64], E f32 [50002][128]. out: f32 [2048]. ws: Bt [50002][64] f32.

#define NROWS   50002
#define KTAGS   64
#define EOS_T   62
#define BOS_T   63
#define TLEN    256
#define TINYV   1e-45f
#define LOG64   4.1588830833596715f

typedef __attribute__((ext_vector_type(8))) short bf16x8;   // 8 bf16
typedef __attribute__((ext_vector_type(4))) float f32x4;

static __device__ __forceinline__ short f2bf(float f) {
    unsigned u = __float_as_uint(f);
    u = (u + 0x7fff + ((u >> 16) & 1)) >> 16;   // round-to-nearest-even
    return (short)u;
}

struct F8 { float v[8]; };

// Emission gather: 8 consecutive tags (quad*8 + 32*kc .. +7) of row w.
static __device__ __forceinline__ F8 load_emis(const float* __restrict__ Bt,
                                               int w, int quad, int kc) {
    const float4* p = (const float4*)(Bt + (size_t)w * KTAGS + quad * 8 + 32 * kc);
    float4 a = p[0], b = p[1];
    F8 r;
    r.v[0]=a.x; r.v[1]=a.y; r.v[2]=a.z; r.v[3]=a.w;
    r.v[4]=b.x; r.v[5]=b.y; r.v[6]=b.z; r.v[7]=b.w;
    return r;
}

// ---------------------------------------------------------------------------
// Kernel 1: Bt[w][k] = exp(ThetaB[k]·E[w]); tags 62,63 -> TINY.
// ThetaB half staged in LDS, read as uniform-address ds_read_b128 (broadcast).
// 32 tags/thread keeps VGPR pressure low (defeats the AGPR-demotion seen R1/R2).
// ---------------------------------------------------------------------------
__global__ __launch_bounds__(256) void emis_table_kernel(
    const float* __restrict__ ThetaB, const float* __restrict__ E,
    float* __restrict__ Bt)
{
    __shared__ float4 sTB[32 * 32];              // 32 tags x 32 d-quads = 16 KB
    const int khalf = blockIdx.x & 1;
    const float4* T4 = (const float4*)ThetaB;
    for (int i = threadIdx.x; i < 1024; i += 256)
        sTB[i] = T4[khalf * 1024 + i];
    __syncthreads();

    const int w = (blockIdx.x >> 1) * 256 + threadIdx.x;
    if (w >= NROWS) return;
    const float4* E4 = (const float4*)E;

    float acc[32];
#pragma unroll
    for (int k = 0; k < 32; ++k) acc[k] = 0.f;

    float4 e = E4[(size_t)w * 32];
    for (int d4 = 0; d4 < 32; ++d4) {
        float4 ec = e;
        if (d4 < 31) e = E4[(size_t)w * 32 + d4 + 1];   // stream-prefetch
#pragma unroll
        for (int k = 0; k < 32; ++k) {
            float4 tb = sTB[k * 32 + d4];               // uniform addr -> broadcast
            acc[k] = fmaf(ec.x, tb.x, acc[k]);
            acc[k] = fmaf(ec.y, tb.y, acc[k]);
            acc[k] = fmaf(ec.z, tb.z, acc[k]);
            acc[k] = fmaf(ec.w, tb.w, acc[k]);
        }
    }

    float4* dst = (float4*)(Bt + (size_t)w * KTAGS + khalf * 32);
#pragma unroll
    for (int q = 0; q < 8; ++q) {
        float4 o;
        o.x = expf(acc[4*q+0]); o.y = expf(acc[4*q+1]);
        o.z = expf(acc[4*q+2]); o.w = expf(acc[4*q+3]);
        if (khalf && q == 7) { o.z = TINYV; o.w = TINYV; }   // tags 62, 63
        dst[q] = o;
    }
}

// ---------------------------------------------------------------------------
// Kernel 2: forward recurrence via MFMA 16x16x32 bf16. One wave = 16 sentences.
//   A-op  = alpha_{t-1} [16 sent x 64 tags]  (2 K-chunks, rebuilt each step)
//   B-op  = A'[i][j] = exp(WA[i][j])*(j!=BOS)/64  (8 constant fragments)
//   D     = alpha_t pre-emission; LDS round-trip [sent][tag] (stride 68, no
//           bank conflicts) converts D-layout -> A-layout; emission applied
//           in fp32 on read-back. 1/64 folded into A'; +255*log64 at the end.
// Per-wave-private LDS tile -> no s_barrier; wave_barrier + in-order DS pipe
// provide the write->read ordering.
// ---------------------------------------------------------------------------
__global__ __launch_bounds__(64) void crf_forward_mfma(
    const int* __restrict__ words, const float* __restrict__ WA,
    const float* __restrict__ Bt, float* __restrict__ out)
{
    __shared__ float lds[16 * 68];
    const int lane = threadIdx.x;
    const int s_lo = lane & 15;          // A/D sentence row | D tag col
    const int quad = lane >> 4;
    const int sbase = blockIdx.x * 16;

    // Constant B fragments: B[k = quad*8+e+32kc][n = s_lo+16nt]
    bf16x8 Bfrag[2][4];
#pragma unroll
    for (int kc = 0; kc < 2; ++kc)
#pragma unroll
        for (int nt = 0; nt < 4; ++nt) {
            const int n = s_lo + 16 * nt;
            const float cm = (n == BOS_T) ? 0.f : 0.015625f;
#pragma unroll
            for (int e = 0; e < 8; ++e) {
                const int k = quad * 8 + e + 32 * kc;
                Bfrag[kc][nt][e] = f2bf(expf(WA[k * 64 + n]) * cm);
            }
        }

    // Epilogue / init vectors in A-frag element positions jt = quad*8+e+32kc
    float aeos[2][8], abos[2][8];
#pragma unroll
    for (int kc = 0; kc < 2; ++kc)
#pragma unroll
        for (int e = 0; e < 8; ++e) {
            const int jt = quad * 8 + e + 32 * kc;
            aeos[kc][e] = expf(WA[jt * 64 + EOS_T]) * 0.015625f;
            abos[kc][e] = (jt == BOS_T) ? 0.f
                          : expf(WA[BOS_T * 64 + jt]) * 0.015625f;
        }

    const int wb = (sbase + s_lo) * TLEN;        // this lane's sentence word row

    // alpha_1 = A'[BOS][j] * emis[1][j]
    const int wd1 = words[wb + 1];
    F8 e1_0 = load_emis(Bt, wd1, quad, 0);
    F8 e1_1 = load_emis(Bt, wd1, quad, 1);

    bf16x8 Afrag[2];
    float acur[2][8];
#pragma unroll
    for (int e = 0; e < 8; ++e) {
        float a0 = abos[0][e] * e1_0.v[e];
        float a1 = abos[1][e] * e1_1.v[e];
        acur[0][e] = a0; acur[1][e] = a1;
        Afrag[0][e] = f2bf(a0); Afrag[1][e] = f2bf(a1);
    }

    // Prefetch pipeline: en = emis[t] at loop entry; w1 = word[t+1], w2 = word[t+2]
    const int wd2 = words[wb + 2];
    F8 en0 = load_emis(Bt, wd2, quad, 0);
    F8 en1 = load_emis(Bt, wd2, quad, 1);
    int w1 = words[wb + 3];
    int w2 = words[wb + 4];

    for (int t = 2; t <= 254; ++t) {
        // alpha_{t-1} @ A'  (4 N-tiles x 2 chained K-chunks)
        f32x4 D[4];
#pragma unroll
        for (int nt = 0; nt < 4; ++nt) {
            f32x4 z = {0.f, 0.f, 0.f, 0.f};
            z = __builtin_amdgcn_mfma_f32_16x16x32_bf16(Afrag[0], Bfrag[0][nt], z, 0, 0, 0);
            D[nt] = __builtin_amdgcn_mfma_f32_16x16x32_bf16(Afrag[1], Bfrag[1][nt], z, 0, 0, 0);
        }

        // issue next-step prefetches early (hide VMEM latency under LDS phase)
        F8 pn0, pn1;
        const bool more = (t < 254);
        if (more) { pn0 = load_emis(Bt, w1, quad, 0); pn1 = load_emis(Bt, w1, quad, 1); }
        const int w3 = (t <= 252) ? words[wb + t + 3] : 0;

        // D-layout -> LDS [sent][tag], stride 68
#pragma unroll
        for (int nt = 0; nt < 4; ++nt)
#pragma unroll
            for (int r = 0; r < 4; ++r)
                lds[(quad * 4 + r) * 68 + s_lo + 16 * nt] = D[nt][r];

        __builtin_amdgcn_wave_barrier();   // order vs reads (same-wave DS is in-order)

        // A-layout read-back * emission -> next A fragments
#pragma unroll
        for (int kc = 0; kc < 2; ++kc) {
            const float4* lp = (const float4*)&lds[s_lo * 68 + quad * 8 + 32 * kc];
            float4 p0 = lp[0], p1 = lp[1];
            float tmp[8] = {p0.x, p0.y, p0.z, p0.w, p1.x, p1.y, p1.z, p1.w};
            const F8& em = kc ? en1 : en0;
#pragma unroll
            for (int e = 0; e < 8; ++e) {
                float a = tmp[e] * em.v[e];
                acur[kc][e] = a;
                Afrag[kc][e] = f2bf(a);
            }
        }
        __builtin_amdgcn_wave_barrier();   // order reads vs next iter's writes

        if (more) { en0 = pn0; en1 = pn1; w1 = w2; w2 = w3; }
    }

    // z[s] = sum_j alpha_254[s][j] * A'[j][EOS]
    float p = 0.f;
#pragma unroll
    for (int kc = 0; kc < 2; ++kc)
#pragma unroll
        for (int e = 0; e < 8; ++e)
            p = fmaf(acur[kc][e], aeos[kc][e], p);
    p += __shfl_xor(p, 16, 64);
    p += __shfl_xor(p, 32, 64);

    if (lane < 16)
        out[sbase + lane] = logf(p) + 255.0f * LOG64;
}

extern "C" void kernel_launch(void* const* d_in, const int* in_sizes, int n_in,
                              void* d_out, int out_size, void* d_ws, size_t ws_size,
                              hipStream_t stream) {
    const int*   words  = (const int*)d_in[0];
    const float* ThetaB = (const float*)d_in[1];
    const float* WA     = (const float*)d_in[2];
    const float* E      = (const float*)d_in[3];
    float*       outp   = (float*)d_out;
    float*       Bt     = (float*)d_ws;          // 50002*64*4 = 12.8 MB

    emis_table_kernel<<<dim3(392), dim3(256), 0, stream>>>(ThetaB, E, Bt);
    crf_forward_mfma<<<dim3(128), dim3(64), 0, stream>>>(words, WA, Bt, outp);
}

// Round 4
// 176.579 us; speedup vs baseline: 1.3048x; 1.3048x over previous
//
#include <hip/hip_runtime.h>

// CRF forward logZ. Inputs: words i32 [2048][256], ThetaB f32 [64][128],
// WA f32 [64][64], E f32 [50002][128]. out: f32 [2048]. ws: Bt [50002][64] f32.
//
// R4 structure:
//  - emis table: thread=word, 32 tags (khalf), ThetaB in LDS, 8-deep E MLP.
//  - recurrence: fwd/bwd split. wave0: alpha_127 = a0 * prod_{t<=127} S diag(e_t);
//    wave1: X = e_128 o w_128, w_t from EOS side. z = (alpha_127 S) . X.
//    Chain = 127 MFMA steps instead of 253.

#define NROWS 50002
#define EOS_T 62
#define BOS_T 63
#define TLEN  256
#define TINYV 1e-45f
#define LOG64 4.1588830833596715f

typedef __attribute__((ext_vector_type(8))) short bf16x8;
typedef __attribute__((ext_vector_type(4))) float f32x4;

struct F8 { float v[8]; };

// round-half-up f32->bf16 pair pack: 2 adds + 1 v_perm (CK idiom)
static __device__ __forceinline__ unsigned pack_bf2(float lo, float hi) {
    unsigned a = __float_as_uint(lo) + 0x8000u;
    unsigned b = __float_as_uint(hi) + 0x8000u;
    return __builtin_amdgcn_perm(b, a, 0x07060302u);
}

static __device__ __forceinline__ bf16x8 pack8(const float t[8]) {
    union { bf16x8 v; unsigned u[4]; } r;
#pragma unroll
    for (int i = 0; i < 4; ++i) r.u[i] = pack_bf2(t[2*i], t[2*i+1]);
    return r.v;
}

static __device__ __forceinline__ F8 load_emis(const float* __restrict__ Bt,
                                               int w, int quad, int kc) {
    const float4* p = (const float4*)(Bt + (size_t)w * 64 + quad * 8 + 32 * kc);
    float4 a = p[0], b = p[1];
    F8 r;
    r.v[0]=a.x; r.v[1]=a.y; r.v[2]=a.z; r.v[3]=a.w;
    r.v[4]=b.x; r.v[5]=b.y; r.v[6]=b.z; r.v[7]=b.w;
    return r;
}

// ---------------------------------------------------------------------------
// Kernel 1: Bt[w][k] = exp(ThetaB[k].E[w]); tags 62,63 -> TINY.
// R1-R3 ran at ~400 GB/s = 1 E-line in flight per wave (latency-bound).
// Fix: 8 float4 in flight (ping-pong), 128-thread blocks, VGPR cap 128.
// ---------------------------------------------------------------------------
__global__ __launch_bounds__(128, 4) void emis_table_kernel(
    const float* __restrict__ ThetaB, const float* __restrict__ E,
    float* __restrict__ Bt)
{
    __shared__ float4 sTB[32 * 32];              // one tag-half: 16 KB
    const int khalf = blockIdx.x & 1;
    const float4* T4 = (const float4*)ThetaB;
    for (int i = threadIdx.x; i < 1024; i += 128)
        sTB[i] = T4[khalf * 1024 + i];
    __syncthreads();

    const int w = (blockIdx.x >> 1) * 128 + threadIdx.x;
    if (w >= NROWS) return;
    const float4* E4 = (const float4*)E + (size_t)w * 32;

    float acc[32];
#pragma unroll
    for (int k = 0; k < 32; ++k) acc[k] = 0.f;

    float4 cur[8], nxt[8];
#pragma unroll
    for (int d = 0; d < 8; ++d) cur[d] = E4[d];

#pragma unroll
    for (int g = 0; g < 4; ++g) {
        if (g < 3) {
#pragma unroll
            for (int d = 0; d < 8; ++d) nxt[d] = E4[(g + 1) * 8 + d];
        }
#pragma unroll
        for (int d = 0; d < 8; ++d) {
            const int d4 = g * 8 + d;
#pragma unroll
            for (int k = 0; k < 32; ++k) {
                float4 tb = sTB[k * 32 + d4];    // uniform addr -> broadcast
                acc[k] = fmaf(cur[d].x, tb.x, acc[k]);
                acc[k] = fmaf(cur[d].y, tb.y, acc[k]);
                acc[k] = fmaf(cur[d].z, tb.z, acc[k]);
                acc[k] = fmaf(cur[d].w, tb.w, acc[k]);
            }
        }
#pragma unroll
        for (int d = 0; d < 8; ++d) cur[d] = nxt[d];
    }

    float4* dst = (float4*)(Bt + (size_t)w * 64 + khalf * 32);
#pragma unroll
    for (int qq = 0; qq < 8; ++qq) {
        float4 o;
        o.x = expf(acc[4*qq+0]); o.y = expf(acc[4*qq+1]);
        o.z = expf(acc[4*qq+2]); o.w = expf(acc[4*qq+3]);
        if (khalf && qq == 7) { o.z = TINYV; o.w = TINYV; }   // tags 62, 63
        dst[qq] = o;
    }
}

// ---------------------------------------------------------------------------
// Kernel 2: fwd/bwd recurrence. Block = 128 threads = 2 waves, 16 sentences.
// wave0 (fwd): Af = alpha, B-op = S.       alpha <- (alpha @ S) o e_t, t up.
// wave1 (bwd): Af = e o w,  B-op = S^T.    w' = S(e_t o w_t) as row form, t down.
// Per step: 8 MFMA (parallel halves + add), LDS transpose (D->A layout,
// stride 68 => max 2-way bank alias = free), emis multiply fp32, perm-pack.
// Emission rows prefetched 2 steps ahead, words 4 ahead, unconditionally.
// ---------------------------------------------------------------------------
__global__ __launch_bounds__(128, 1) void crf_fwdbwd(
    const int* __restrict__ words, const float* __restrict__ WA,
    const float* __restrict__ Bt, float* __restrict__ out)
{
    __shared__ float tiles[2][16 * 68];
    const int lane = threadIdx.x & 63;
    const int wv   = threadIdx.x >> 6;           // 0 = fwd, 1 = bwd
    const int l    = lane & 15;
    const int q    = lane >> 4;
    const int sbase = blockIdx.x * 16;
    float* tile = tiles[wv];

    // Constant B fragments. S[i][j] = exp(WA[i][j]) * (j!=BOS)/64.
    // fwd: B[k][n] = S[k][n];  bwd: B[k][n] = S^T[k][n] = S[n][k].
    bf16x8 Bf[2][4];
#pragma unroll
    for (int kc = 0; kc < 2; ++kc)
#pragma unroll
        for (int nt = 0; nt < 4; ++nt) {
            const int n = l + 16 * nt;
            float tmp[8];
#pragma unroll
            for (int e = 0; e < 8; ++e) {
                const int k = q * 8 + e + 32 * kc;
                const int i = wv ? n : k;
                const int j = wv ? k : n;
                tmp[e] = expf(WA[i * 64 + j]) * ((j == BOS_T) ? 0.f : 0.015625f);
            }
            Bf[kc][nt] = pack8(tmp);
        }

    // Init vector at jt = q*8+e+32kc: fwd S[BOS][jt], bwd S[jt][EOS].
    float g[2][8];
#pragma unroll
    for (int kc = 0; kc < 2; ++kc)
#pragma unroll
        for (int e = 0; e < 8; ++e) {
            const int jt = q * 8 + e + 32 * kc;
            g[kc][e] = wv ? expf(WA[jt * 64 + EOS_T]) * 0.015625f
                          : expf(WA[BOS_T * 64 + jt]) * ((jt == BOS_T) ? 0.f : 0.015625f);
        }

    const int wb    = (sbase + l) * TLEN;
    const int tini  = wv ? 254 : 1;              // init emis index
    const int tbase = wv ? 253 : 2;              // iter-0 emis index
    const int sgn   = wv ? -1 : 1;

    // word + emission pipeline (2-deep emis, 4-deep words)
    const int wI  = words[wb + tini];
    const int wC0 = words[wb + tbase];
    const int wC1 = words[wb + tbase + sgn];
    int wN0 = words[wb + tbase + 2 * sgn];       // word for iter i+2
    int wN1 = words[wb + tbase + 3 * sgn];       // word for iter i+3
    F8 eI0 = load_emis(Bt, wI,  q, 0), eI1 = load_emis(Bt, wI,  q, 1);
    F8 eA0 = load_emis(Bt, wC0, q, 0), eA1 = load_emis(Bt, wC0, q, 1);
    F8 eB0 = load_emis(Bt, wC1, q, 0), eB1 = load_emis(Bt, wC1, q, 1);

    // init state: vals = g o e_init
    F8 vals0, vals1;
#pragma unroll
    for (int e = 0; e < 8; ++e) {
        vals0.v[e] = g[0][e] * eI0.v[e];
        vals1.v[e] = g[1][e] * eI1.v[e];
    }
    bf16x8 Af0 = pack8(vals0.v), Af1 = pack8(vals1.v);

    auto substep = [&](F8& em0, F8& em1, int wNext) {
        // D = Af0@Bf0 + Af1@Bf1 (independent MFMAs, VALU add — no MFMA chain)
        f32x4 D[4];
#pragma unroll
        for (int nt = 0; nt < 4; ++nt) {
            const f32x4 z = {0.f, 0.f, 0.f, 0.f};
            f32x4 da = __builtin_amdgcn_mfma_f32_16x16x32_bf16(Af0, Bf[0][nt], z, 0, 0, 0);
            f32x4 db = __builtin_amdgcn_mfma_f32_16x16x32_bf16(Af1, Bf[1][nt], z, 0, 0, 0);
            D[nt] = da + db;
        }
        // prefetch emis for iter i+2 (word loaded 2 iters ago; 2-step slack)
        F8 p0 = load_emis(Bt, wNext, q, 0), p1 = load_emis(Bt, wNext, q, 1);
        // D-layout -> LDS [sent][tag] (stride 68)
#pragma unroll
        for (int nt = 0; nt < 4; ++nt)
#pragma unroll
            for (int r = 0; r < 4; ++r)
                tile[(q * 4 + r) * 68 + l + 16 * nt] = D[nt][r];
        __builtin_amdgcn_wave_barrier();
        // A-layout read-back
        const float4* lp0 = (const float4*)&tile[l * 68 + q * 8];
        const float4* lp1 = (const float4*)&tile[l * 68 + q * 8 + 32];
        float4 xa = lp0[0], xb = lp0[1], xc = lp1[0], xd = lp1[1];
        __builtin_amdgcn_wave_barrier();
        float xs0[8] = {xa.x,xa.y,xa.z,xa.w,xb.x,xb.y,xb.z,xb.w};
        float xs1[8] = {xc.x,xc.y,xc.z,xc.w,xd.x,xd.y,xd.z,xd.w};
#pragma unroll
        for (int e = 0; e < 8; ++e) {
            vals0.v[e] = xs0[e] * em0.v[e];
            vals1.v[e] = xs1[e] * em1.v[e];
        }
        Af0 = pack8(vals0.v); Af1 = pack8(vals1.v);
        em0 = p0; em1 = p1;                      // rotate (static under unroll-2)
    };

    for (int i = 0; i < 126; i += 2) {
        substep(eA0, eA1, wN0);
        wN0 = words[wb + tbase + sgn * (i + 4)];
        substep(eB0, eB1, wN1);
        wN1 = words[wb + tbase + sgn * (i + 5)];
    }

    if (wv == 0) {
        // extra step: y = alpha_127 @ S  -> tile 0 (no emission)
        f32x4 D[4];
#pragma unroll
        for (int nt = 0; nt < 4; ++nt) {
            const f32x4 z = {0.f, 0.f, 0.f, 0.f};
            f32x4 da = __builtin_amdgcn_mfma_f32_16x16x32_bf16(Af0, Bf[0][nt], z, 0, 0, 0);
            f32x4 db = __builtin_amdgcn_mfma_f32_16x16x32_bf16(Af1, Bf[1][nt], z, 0, 0, 0);
            D[nt] = da + db;
        }
#pragma unroll
        for (int nt = 0; nt < 4; ++nt)
#pragma unroll
            for (int r = 0; r < 4; ++r)
                tiles[0][(q * 4 + r) * 68 + l + 16 * nt] = D[nt][r];
    }
    __syncthreads();
    if (wv == 1) {
        // z = y . (e_128 o w_128), both in [sent=l][tag=q*8+e+32kc] positions
        float p = 0.f;
#pragma unroll
        for (int e = 0; e < 8; ++e) {
            p = fmaf(vals0.v[e], tiles[0][l * 68 + q * 8 + e], p);
            p = fmaf(vals1.v[e], tiles[0][l * 68 + q * 8 + 32 + e], p);
        }
        p += __shfl_xor(p, 16, 64);
        p += __shfl_xor(p, 32, 64);
        if (lane < 16)
            out[sbase + l] = logf(p) + 255.0f * LOG64;
    }
}

extern "C" void kernel_launch(void* const* d_in, const int* in_sizes, int n_in,
                              void* d_out, int out_size, void* d_ws, size_t ws_size,
                              hipStream_t stream) {
    const int*   words  = (const int*)d_in[0];
    const float* ThetaB = (const float*)d_in[1];
    const float* WA     = (const float*)d_in[2];
    const float* E      = (const float*)d_in[3];
    float*       outp   = (float*)d_out;
    float*       Bt     = (float*)d_ws;          // 50002*64*4 = 12.8 MB

    // 391 word-blocks (128 words each) x 2 tag-halves
    emis_table_kernel<<<dim3(782), dim3(128), 0, stream>>>(ThetaB, E, Bt);
    // 128 blocks x (fwd wave + bwd wave), 16 sentences/block
    crf_fwdbwd<<<dim3(128), dim3(128), 0, stream>>>(words, WA, Bt, outp);
}

// Round 5
// 139.653 us; speedup vs baseline: 1.6498x; 1.2644x over previous
//
#include <hip/hip_runtime.h>

// CRF forward logZ. Inputs: words i32 [2048][256], ThetaB f32 [64][128],
// WA f32 [64][64], E f32 [50002][128]. out: f32 [2048].
// ws: Bt table in bf16, [50002][64] = 6.4 MB.
//
// R5: (1) recurrence uses mfma_16x16x16bf16_1k with state as B-operand:
//     D-layout tag set == next B-frag K set -> in-register step, NO LDS.
//     (2) emission table stored bf16 (halves gather footprint, ~L2-resident),
//     prefetched 6 steps deep in registers (unroll-6 ring).
//     (3) emis table built by MFMA GEMM (HBM-bound ~32 MB, no LDS).

#define NROWS 50002
#define EOS_T 62
#define BOS_T 63
#define TLEN  256
#define LOG64 4.1588830833596715f

typedef __attribute__((ext_vector_type(4))) short bf16x4;
typedef __attribute__((ext_vector_type(8))) short bf16x8;
typedef __attribute__((ext_vector_type(4))) float f32x4;

// round-half-up f32->bf16 pair pack (2 add + 1 perm); lo in low 16 bits
static __device__ __forceinline__ unsigned pack_bf2(float lo, float hi) {
    unsigned a = __float_as_uint(lo) + 0x8000u;
    unsigned b = __float_as_uint(hi) + 0x8000u;
    return __builtin_amdgcn_perm(b, a, 0x07060302u);
}
static __device__ __forceinline__ bf16x8 pack8(float4 a, float4 b) {
    union { bf16x8 v; unsigned u[4]; } r;
    r.u[0] = pack_bf2(a.x, a.y); r.u[1] = pack_bf2(a.z, a.w);
    r.u[2] = pack_bf2(b.x, b.y); r.u[3] = pack_bf2(b.z, b.w);
    return r.v;
}
static __device__ __forceinline__ bf16x4 pack4(float f0, float f1, float f2, float f3) {
    union { bf16x4 v; unsigned u[2]; } r;
    r.u[0] = pack_bf2(f0, f1); r.u[1] = pack_bf2(f2, f3);
    return r.v;
}

// ---------------------------------------------------------------------------
// Kernel 1: Btb[w][k] = bf16(exp(ThetaB[k].E[w])); tags 62,63 -> 0.
// MFMA GEMM, D[tag = mt*16+q*4+r][word = l]. A = ThetaB (constant per wave,
// amortized over 4 word-tiles), B = E rows loaded in native fragment layout.
// ---------------------------------------------------------------------------
__global__ __launch_bounds__(64) void emis_mfma(
    const float* __restrict__ ThetaB, const float* __restrict__ E,
    uint2* __restrict__ Btb)
{
    const int l = threadIdx.x & 15;
    const int q = threadIdx.x >> 4;

    // A-frags: A[m=l -> tag mt*16+l][k = q*8+j+32kc] = ThetaB[tag][k]
    bf16x8 Af[4][4];
#pragma unroll
    for (int mt = 0; mt < 4; ++mt)
#pragma unroll
        for (int kc = 0; kc < 4; ++kc) {
            const float4* tp = (const float4*)ThetaB + (mt * 16 + l) * 32 + kc * 8 + q * 2;
            Af[mt][kc] = pack8(tp[0], tp[1]);
        }

    const int base0 = blockIdx.x * 64;
#pragma unroll
    for (int it = 0; it < 4; ++it) {
        const int row  = base0 + it * 16 + l;
        const int rowc = row < NROWS ? row : NROWS - 1;
        // B-frags: B[k = q*8+j+32kc][n = l] = E[row][k]
        const float4* ep = (const float4*)E + (size_t)rowc * 32 + q * 2;
        bf16x8 Bf[4];
#pragma unroll
        for (int kc = 0; kc < 4; ++kc)
            Bf[kc] = pack8(ep[kc * 8], ep[kc * 8 + 1]);

        f32x4 D[4];
#pragma unroll
        for (int mt = 0; mt < 4; ++mt) { f32x4 z = {0.f, 0.f, 0.f, 0.f}; D[mt] = z; }
#pragma unroll
        for (int kc = 0; kc < 4; ++kc)
#pragma unroll
            for (int mt = 0; mt < 4; ++mt)
                D[mt] = __builtin_amdgcn_mfma_f32_16x16x32_bf16(Af[mt][kc], Bf[kc], D[mt], 0, 0, 0);

        if (row < NROWS) {
#pragma unroll
            for (int mt = 0; mt < 4; ++mt) {
                float v0 = expf(D[mt][0]), v1 = expf(D[mt][1]);
                float v2 = expf(D[mt][2]), v3 = expf(D[mt][3]);
                if (mt == 3 && q == 3) { v2 = 0.f; v3 = 0.f; }   // tags 62, 63
                uint2 o; o.x = pack_bf2(v0, v1); o.y = pack_bf2(v2, v3);
                Btb[(size_t)row * 16 + mt * 4 + q] = o;          // [w][tag] bf16
            }
        }
    }
}

// ---------------------------------------------------------------------------
// Kernel 2: fwd/bwd recurrence, fully in registers.
// State X = B-operand: X[tag = kc*16+q*4+j][sent = l], bf16x4 per kc.
// fwd (wv=0): A = S^T (mask on m), X' = (S^T X) o e_t, t = 2..127.
// bwd (wv=1): A = S   (mask on k), X' = e_t o (S X),  t = 253..128.
// D[mt] tag set == B-frag[kc=mt] K set -> register handoff, no LDS per step.
// Emission ring: 6 bf16 buffers; words fetched 12 steps ahead (all in-bounds).
// Join: z = (S^T alpha_127) . (e_128 o q_129) via one LDS tile + dot.
// ---------------------------------------------------------------------------
__global__ __launch_bounds__(128) void crf_fwdbwd(
    const int* __restrict__ words, const float* __restrict__ WA,
    const uint2* __restrict__ Btb, float* __restrict__ out)
{
    __shared__ float ytile[16 * 68];
    const int lane  = threadIdx.x & 63;
    const int wv    = threadIdx.x >> 6;          // 0 = fwd, 1 = bwd
    const int l     = lane & 15;
    const int q     = lane >> 4;
    const int sbase = blockIdx.x * 16;

    // Transition A-frags. S[i][j] = exp(WA[i][j]) * (j != BOS)/64.
    bf16x4 Sf[4][4];
#pragma unroll
    for (int mt = 0; mt < 4; ++mt)
#pragma unroll
        for (int kc = 0; kc < 4; ++kc) {
            float t[4];
#pragma unroll
            for (int j = 0; j < 4; ++j) {
                const int mg = mt * 16 + l;          // m index
                const int kg = kc * 16 + q * 4 + j;  // k index
                const int ii = wv ? mg : kg;         // WA row
                const int jj = wv ? kg : mg;         // WA col (masked: S's j)
                t[j] = (jj == BOS_T) ? 0.f : expf(WA[ii * 64 + jj]) * 0.015625f;
            }
            Sf[mt][kc] = pack4(t[0], t[1], t[2], t[3]);
        }

    // Init vector in X-layout, tag jt = kc*16 + q*4 + e:
    // fwd: S[BOS][jt] (alpha_1 pre-emission); bwd: S[jt][EOS] (q_255).
    float g[4][4];
#pragma unroll
    for (int kc = 0; kc < 4; ++kc)
#pragma unroll
        for (int e = 0; e < 4; ++e) {
            const int jt = kc * 16 + q * 4 + e;
            g[kc][e] = wv ? expf(WA[jt * 64 + EOS_T]) * 0.015625f
                          : ((jt == BOS_T) ? 0.f : expf(WA[BOS_T * 64 + jt]) * 0.015625f);
        }

    const int wb   = (sbase + l) * TLEN;
    const int tdir = wv ? -1 : 1;
    const int t0   = wv ? 254 : 1;

    auto eload = [&](int w, uint2 (&buf)[4]) {
#pragma unroll
        for (int kc = 0; kc < 4; ++kc)
            buf[kc] = Btb[(size_t)w * 16 + kc * 4 + q];
    };

    uint2 ei[4], ebA[4], ebB[4], ebC[4], ebD[4], ebE[4], ebF[4];
    eload(words[wb + t0], ei);
    eload(words[wb + t0 + 1 * tdir], ebA);   // emis for step 0
    eload(words[wb + t0 + 2 * tdir], ebB);
    eload(words[wb + t0 + 3 * tdir], ebC);
    eload(words[wb + t0 + 4 * tdir], ebD);
    eload(words[wb + t0 + 5 * tdir], ebE);
    eload(words[wb + t0 + 6 * tdir], ebF);   // emis for step 5
    int wdA = words[wb + t0 + 7 * tdir];     // word for step 6
    int wdB = words[wb + t0 + 8 * tdir];
    int wdC = words[wb + t0 + 9 * tdir];
    int wdD = words[wb + t0 + 10 * tdir];
    int wdE = words[wb + t0 + 11 * tdir];
    int wdF = words[wb + t0 + 12 * tdir];    // word for step 11

    // X init = g o e_{t0}
    bf16x4 X[4];
#pragma unroll
    for (int kc = 0; kc < 4; ++kc) {
        float f0 = __uint_as_float(ei[kc].x << 16)         * g[kc][0];
        float f1 = __uint_as_float(ei[kc].x & 0xffff0000u) * g[kc][1];
        float f2 = __uint_as_float(ei[kc].y << 16)         * g[kc][2];
        float f3 = __uint_as_float(ei[kc].y & 0xffff0000u) * g[kc][3];
        X[kc] = pack4(f0, f1, f2, f3);
    }

    float xf[4][4];                          // last step's f32 products (join)

    // substep consuming step i: refills eb for step i+6, fetches word i+12
    auto substep = [&](uint2 (&eb)[4], int& wd, int widx) {
        f32x4 D[4];
#pragma unroll
        for (int mt = 0; mt < 4; ++mt) { f32x4 z = {0.f, 0.f, 0.f, 0.f}; D[mt] = z; }
#pragma unroll
        for (int kc = 0; kc < 4; ++kc)
#pragma unroll
            for (int mt = 0; mt < 4; ++mt)
                D[mt] = __builtin_amdgcn_mfma_f32_16x16x16bf16_1k(Sf[mt][kc], X[kc], D[mt], 0, 0, 0);
#pragma unroll
        for (int kc = 0; kc < 4; ++kc) {
            float f0 = __uint_as_float(eb[kc].x << 16);
            float f1 = __uint_as_float(eb[kc].x & 0xffff0000u);
            float f2 = __uint_as_float(eb[kc].y << 16);
            float f3 = __uint_as_float(eb[kc].y & 0xffff0000u);
            xf[kc][0] = D[kc][0] * f0;  xf[kc][1] = D[kc][1] * f1;
            xf[kc][2] = D[kc][2] * f2;  xf[kc][3] = D[kc][3] * f3;
            X[kc] = pack4(xf[kc][0], xf[kc][1], xf[kc][2], xf[kc][3]);
        }
        eload(wd, eb);
        wd = words[wb + widx];
    };

    // 126 steps; word index bounds: fwd max t0+139=140<256, bwd min 254-138>=0
    for (int i = 0; i < 126; i += 6) {
        substep(ebA, wdA, t0 + tdir * (i + 13));
        substep(ebB, wdB, t0 + tdir * (i + 14));
        substep(ebC, wdC, t0 + tdir * (i + 15));
        substep(ebD, wdD, t0 + tdir * (i + 16));
        substep(ebE, wdE, t0 + tdir * (i + 17));
        substep(ebF, wdF, t0 + tdir * (i + 18));
    }

    if (wv == 0) {
        // extra step: Y = S^T alpha_127 (no emission) -> LDS
        f32x4 D[4];
#pragma unroll
        for (int mt = 0; mt < 4; ++mt) { f32x4 z = {0.f, 0.f, 0.f, 0.f}; D[mt] = z; }
#pragma unroll
        for (int kc = 0; kc < 4; ++kc)
#pragma unroll
            for (int mt = 0; mt < 4; ++mt)
                D[mt] = __builtin_amdgcn_mfma_f32_16x16x16bf16_1k(Sf[mt][kc], X[kc], D[mt], 0, 0, 0);
#pragma unroll
        for (int mt = 0; mt < 4; ++mt) {
            float4 o = {D[mt][0], D[mt][1], D[mt][2], D[mt][3]};
            *(float4*)&ytile[l * 68 + mt * 16 + q * 4] = o;
        }
    }
    __syncthreads();
    if (wv == 1) {
        // z[s] = sum_tag Y[tag][s] * X128[tag][s]
        float p = 0.f;
#pragma unroll
        for (int mt = 0; mt < 4; ++mt)
#pragma unroll
            for (int r = 0; r < 4; ++r)
                p = fmaf(ytile[l * 68 + mt * 16 + q * 4 + r], xf[mt][r], p);
        p += __shfl_xor(p, 16, 64);
        p += __shfl_xor(p, 32, 64);
        if (lane < 16)
            out[sbase + l] = logf(p) + 255.0f * LOG64;
    }
}

extern "C" void kernel_launch(void* const* d_in, const int* in_sizes, int n_in,
                              void* d_out, int out_size, void* d_ws, size_t ws_size,
                              hipStream_t stream) {
    const int*   words  = (const int*)d_in[0];
    const float* ThetaB = (const float*)d_in[1];
    const float* WA     = (const float*)d_in[2];
    const float* E      = (const float*)d_in[3];
    float*       outp   = (float*)d_out;
    uint2*       Btb    = (uint2*)d_ws;          // 50002*128 B = 6.4 MB

    // 782 blocks x 1 wave x 4 word-tiles = 50048 >= 50002 rows
    emis_mfma<<<dim3(782), dim3(64), 0, stream>>>(ThetaB, E, Btb);
    // 128 blocks x (fwd wave + bwd wave), 16 sentences each
    crf_fwdbwd<<<dim3(128), dim3(128), 0, stream>>>(words, WA, Btb, outp);
}